// Round 5
// baseline (444.866 us; speedup 1.0000x reference)
//
#include <hip/hip_runtime.h>
#include <cmath>

#define IN_CH 128
#define OUT_CH 128
#define KDIM 512           // Z row: x(128) | sum(128) | mean(128) | max(128)
#define NGEMM 384          // gemm N: permuted (wavegrp, section, ocol)

typedef __attribute__((ext_vector_type(8))) short bfrag;   // 8 bf16 in 4 VGPRs
typedef __attribute__((ext_vector_type(4))) float f32x4;

// float -> bf16 round-to-nearest-even (bit pattern)
__device__ __forceinline__ unsigned short f2bf(float f) {
    unsigned int u = __float_as_uint(f);
    return (unsigned short)((u + 0x7FFFu + ((u >> 16) & 1u)) >> 16);
}
__device__ __forceinline__ float bf2f(unsigned short h) {
    return __uint_as_float(((unsigned int)h) << 16);
}

// ---------------- CSR build ----------------

__global__ void degree_kernel(const int* __restrict__ ei, int* __restrict__ degree, int E) {
    int e = blockIdx.x * blockDim.x + threadIdx.x;
    if (e < E) atomicAdd(&degree[ei[E + e]], 1);
}

__global__ __launch_bounds__(1024) void scan_kernel(const int* __restrict__ degree,
                                                    int* __restrict__ offsets,
                                                    float* __restrict__ logsum, int n) {
    const int T = 1024;
    int tid = threadIdx.x;
    int chunk = (n + T - 1) / T;
    int beg = min(tid * chunk, n);
    int end = min(beg + chunk, n);
    int s = 0;
    float ls = 0.f;
    for (int i = beg; i < end; ++i) {
        int d = degree[i];
        s += d;
        ls += logf((float)d + 2.0f);   // == log1p(d+1)
    }
    __shared__ int part[T];
    __shared__ float fl[T];
    part[tid] = s;
    fl[tid] = ls;
    __syncthreads();
    for (int off = 1; off < T; off <<= 1) {
        int v = (tid >= off) ? part[tid - off] : 0;
        __syncthreads();
        part[tid] += v;
        __syncthreads();
    }
    for (int off = T / 2; off > 0; off >>= 1) {
        if (tid < off) fl[tid] += fl[tid + off];
        __syncthreads();
    }
    if (tid == 0) logsum[0] = fl[0];
    int prefix = (tid == 0) ? 0 : part[tid - 1];
    for (int i = beg; i < end; ++i) {
        offsets[i] = prefix;
        prefix += degree[i];
    }
    if (tid == T - 1) offsets[n] = prefix;
}

__global__ void fill_kernel(const int* __restrict__ ei, const int* __restrict__ offsets,
                            int* __restrict__ cursor, int* __restrict__ csr_src, int E) {
    int e = blockIdx.x * blockDim.x + threadIdx.x;
    if (e < E) {
        int src = ei[e];
        int dst = ei[E + e];
        int pos = offsets[dst] + atomicAdd(&cursor[dst], 1);
        csr_src[pos] = src;
    }
}

// ---------------- Aggregation: one WAVE per node, lane = 2 channels ----------------
// Unroll-8: 8 independent gather chains in flight per wave to cover L2/L3 latency.

__global__ __launch_bounds__(256) void agg_kernel(const float* __restrict__ x,
                                                  const int* __restrict__ csr_src,
                                                  const int* __restrict__ offsets,
                                                  const float* __restrict__ logsum,
                                                  unsigned short* __restrict__ Zhi,
                                                  unsigned short* __restrict__ Zlo,
                                                  float* __restrict__ ampv,
                                                  float* __restrict__ attv,
                                                  int N, int Mpad) {
    int node = (blockIdx.x * 256 + threadIdx.x) >> 6;
    int lane = threadIdx.x & 63;
    if (node >= Mpad) return;
    long zoff = (long)node * KDIM + lane * 2;
    if (node >= N) {   // pad rows: zero so GEMM reads are harmless
        #pragma unroll
        for (int sec = 0; sec < 4; ++sec) {
            *(unsigned int*)&Zhi[zoff + sec * 128] = 0u;
            *(unsigned int*)&Zlo[zoff + sec * 128] = 0u;
        }
        return;
    }
    int beg = offsets[node], end = offsets[node + 1];
    const float NEG = -3.402823466e38f;
    float2 s[8], m[8];
    #pragma unroll
    for (int u = 0; u < 8; ++u) { s[u] = make_float2(0.f, 0.f); m[u] = make_float2(NEG, NEG); }
    int i = beg;
    for (; i + 8 <= end; i += 8) {
        int idx[8];
        #pragma unroll
        for (int u = 0; u < 8; ++u) idx[u] = csr_src[i + u];
        float2 v[8];
        #pragma unroll
        for (int u = 0; u < 8; ++u) v[u] = *(const float2*)&x[(long)idx[u] * IN_CH + lane * 2];
        #pragma unroll
        for (int u = 0; u < 8; ++u) {
            s[u].x += v[u].x; s[u].y += v[u].y;
            m[u].x = fmaxf(m[u].x, v[u].x); m[u].y = fmaxf(m[u].y, v[u].y);
        }
    }
    for (; i < end; ++i) {
        int n0 = csr_src[i];
        float2 v0 = *(const float2*)&x[(long)n0 * IN_CH + lane * 2];
        s[0].x += v0.x; s[0].y += v0.y;
        m[0].x = fmaxf(m[0].x, v0.x); m[0].y = fmaxf(m[0].y, v0.y);
    }
    #pragma unroll
    for (int u = 4; u < 8; ++u) {
        s[u - 4].x += s[u].x; s[u - 4].y += s[u].y;
        m[u - 4].x = fmaxf(m[u - 4].x, m[u].x); m[u - 4].y = fmaxf(m[u - 4].y, m[u].y);
    }
    float2 sum = make_float2((s[0].x + s[1].x) + (s[2].x + s[3].x),
                             (s[0].y + s[1].y) + (s[2].y + s[3].y));
    float2 mx = make_float2(fmaxf(fmaxf(m[0].x, m[1].x), fmaxf(m[2].x, m[3].x)),
                            fmaxf(fmaxf(m[0].y, m[1].y), fmaxf(m[2].y, m[3].y)));
    int deg = end - beg;
    float inv = 1.0f / fmaxf((float)deg, 1.0f);
    float2 mean = make_float2(sum.x * inv, sum.y * inv);
    if (deg == 0) { mx.x = 0.f; mx.y = 0.f; }
    float2 xv = *(const float2*)&x[(long)node * IN_CH + lane * 2];

    float2 secs[4] = { xv, sum, mean, mx };
    #pragma unroll
    for (int sec = 0; sec < 4; ++sec) {
        float a = secs[sec].x, b = secs[sec].y;
        unsigned short ha = f2bf(a), hb = f2bf(b);
        float la = a - bf2f(ha), lb = b - bf2f(hb);
        unsigned int hi = (unsigned int)ha | ((unsigned int)hb << 16);
        unsigned int lo = (unsigned int)f2bf(la) | ((unsigned int)f2bf(lb) << 16);
        *(unsigned int*)&Zhi[zoff + sec * 128] = hi;
        *(unsigned int*)&Zlo[zoff + sec * 128] = lo;
    }
    if (lane == 0) {
        float ref = fmaxf(logsum[0] / (float)N, 1.0f);
        float dt = log1pf((float)deg + 1.0f);
        ampv[node] = dt / ref;
        attv[node] = ref / fmaxf(dt, 1e-6f);
    }
}

// ---------------- Weight build: frag-major B, bf16 hi/lo --------------------------
// Bf flat idx = ((st*16 + ks)*64 + lane)*8 + e  ->  W^T[jp][k] where
// r16=lane&15, q=lane>>4, jp = st*16 + r16, k = ks*32 + q*8 + e.
// jp -> (wgrp = jp/96, s = (jp%96)>>5, o = jp&31), ocol = wgrp*32 + o.
// Stripe st = wgrp*6 + s*2 + h covers section s, ocols wgrp*32 + h*16 + [0,16).

__global__ void wbuild_kernel(const float* __restrict__ Wmsg, const float* __restrict__ Wroot,
                              unsigned short* __restrict__ Whi, unsigned short* __restrict__ Wlo) {
    int idx = blockIdx.x * 256 + threadIdx.x;
    if (idx >= NGEMM * KDIM) return;
    int e = idx & 7;
    int lane = (idx >> 3) & 63;
    int t2 = idx >> 9;
    int ks = t2 & 15;
    int st = t2 >> 4;                 // 0..23
    int r16 = lane & 15, q = lane >> 4;
    int jp = st * 16 + r16;
    int k = ks * 32 + q * 8 + e;
    int wgrp = jp / 96;
    int rem = jp - wgrp * 96;
    int s = rem >> 5;
    int ocol = wgrp * 32 + (rem & 31);
    float v;
    if (k < 128) {
        v = (s == 0) ? Wroot[ocol * 128 + k] : 0.f;
    } else {
        int a = (k - 128) >> 7;
        int c = (k - 128) & 127;
        v = Wmsg[ocol * 1152 + (a * 3 + s) * 128 + c];
    }
    unsigned short h = f2bf(v);
    Whi[idx] = h;
    Wlo[idx] = f2bf(v - bf2f(h));
}

// ---------------- MFMA GEMM, zero LDS, 8 waves/block for occupancy ---------------
// out[M,128] = epilogue( Z[M,512] @ Wt^T ).  Block = 8 waves (512 thr), 64 rows.
// Wave w owns stripes {wbase, wbase+2, wbase+4}, wbase = (w>>1)*6 + (w&1)
//   = sections 0,1,2 of output cols (w>>1)*32 + (w&1)*16 + [0,16).
// acc[4][3] = 48 AGPRs; ~60 arch VGPRs -> 4 waves/SIMD (vs 2 in round 4).

__global__ __launch_bounds__(512, 4) void gemm_kernel(const unsigned short* __restrict__ Zhi,
                                                      const unsigned short* __restrict__ Zlo,
                                                      const unsigned short* __restrict__ Whi,
                                                      const unsigned short* __restrict__ Wlo,
                                                      const float* __restrict__ ampv,
                                                      const float* __restrict__ attv,
                                                      const float* __restrict__ bmsg,
                                                      const float* __restrict__ broot,
                                                      float* __restrict__ out, int M) {
    const int tid = threadIdx.x;
    const int w = tid >> 6;          // 0..7
    const int lane = tid & 63;
    const int row0 = blockIdx.x * 64;
    const int r16 = lane & 15, q = lane >> 4;
    const int wbase = (w >> 1) * 6 + (w & 1);

    f32x4 acc[4][3] = {};

    const unsigned short* pah[4];
    const unsigned short* pal[4];
    #pragma unroll
    for (int mt = 0; mt < 4; ++mt) {
        long o = (long)(row0 + mt * 16 + r16) * KDIM + q * 8;
        pah[mt] = Zhi + o;
        pal[mt] = Zlo + o;
    }
    // B: idx(st,ks,lane,e) = st*8192 + ks*512 + lane*8 + e
    const unsigned short* pbh = Whi + (long)wbase * 8192 + lane * 8;
    const unsigned short* pbl = Wlo + (long)wbase * 8192 + lane * 8;

    for (int ks = 0; ks < 16; ++ks) {
        bfrag ah[4], al[4], bh[3], bl[3];
        #pragma unroll
        for (int mt = 0; mt < 4; ++mt) {
            ah[mt] = *(const bfrag*)pah[mt];
            al[mt] = *(const bfrag*)pal[mt];
            pah[mt] += 32;
            pal[mt] += 32;
        }
        #pragma unroll
        for (int t = 0; t < 3; ++t) {
            bh[t] = *(const bfrag*)(pbh + (long)t * 16384);
            bl[t] = *(const bfrag*)(pbl + (long)t * 16384);
        }
        pbh += 512;
        pbl += 512;
        #pragma unroll
        for (int t = 0; t < 3; ++t) {
            #pragma unroll
            for (int mt = 0; mt < 4; ++mt) {
                acc[mt][t] = __builtin_amdgcn_mfma_f32_16x16x32_bf16(ah[mt], bh[t], acc[mt][t], 0, 0, 0);
                acc[mt][t] = __builtin_amdgcn_mfma_f32_16x16x32_bf16(ah[mt], bl[t], acc[mt][t], 0, 0, 0);
                acc[mt][t] = __builtin_amdgcn_mfma_f32_16x16x32_bf16(al[mt], bh[t], acc[mt][t], 0, 0, 0);
            }
        }
    }

    // fused epilogue: C/D layout col=lane&15, row=quad*4+reg  (verified m89/m91)
    const int col = (w >> 1) * 32 + (w & 1) * 16 + r16;
    const float bias = bmsg[col] + broot[col];
    #pragma unroll
    for (int mt = 0; mt < 4; ++mt) {
        #pragma unroll
        for (int r = 0; r < 4; ++r) {
            int row = row0 + mt * 16 + q * 4 + r;
            if (row < M) {
                float v = acc[mt][0][r]
                        + ampv[row] * acc[mt][1][r]
                        + attv[row] * acc[mt][2][r] + bias;
                out[(long)row * OUT_CH + col] = v;
            }
        }
    }
}

// ---------------- Launch ----------------

extern "C" void kernel_launch(void* const* d_in, const int* in_sizes, int n_in,
                              void* d_out, int out_size, void* d_ws, size_t ws_size,
                              hipStream_t stream) {
    const float* x     = (const float*)d_in[0];
    const int*   ei    = (const int*)d_in[1];
    const float* Wmsg  = (const float*)d_in[2];
    const float* bmsg  = (const float*)d_in[3];
    const float* Wroot = (const float*)d_in[4];
    const float* broot = (const float*)d_in[5];
    float* out = (float*)d_out;

    int N = in_sizes[0] / IN_CH;           // 50000
    int E = in_sizes[1] / 2;               // 600000
    int nblk = (N + 63) / 64;              // 782
    int Mpad = nblk * 64;                  // 50048

    char* ws = (char*)d_ws;
    size_t off = 0;
    auto alloc = [&](size_t bytes) -> void* {
        void* p = ws + off;
        off = (off + bytes + 255) & ~(size_t)255;
        return p;
    };
    int* degree  = (int*)alloc((size_t)N * 4);
    int* offsets = (int*)alloc((size_t)(N + 1) * 4);
    int* cursor  = (int*)alloc((size_t)N * 4);
    float* logsum = (float*)alloc(4);
    int* csr_src = (int*)alloc((size_t)E * 4);
    unsigned short* Whi = (unsigned short*)alloc((size_t)NGEMM * KDIM * 2);
    unsigned short* Wlo = (unsigned short*)alloc((size_t)NGEMM * KDIM * 2);
    unsigned short* Zhi = (unsigned short*)alloc((size_t)Mpad * KDIM * 2);
    unsigned short* Zlo = (unsigned short*)alloc((size_t)Mpad * KDIM * 2);
    float* ampv = (float*)alloc((size_t)N * 4);
    float* attv = (float*)alloc((size_t)N * 4);

    hipMemsetAsync(degree, 0, (size_t)N * 4, stream);
    hipMemsetAsync(cursor, 0, (size_t)N * 4, stream);

    degree_kernel<<<(E + 255) / 256, 256, 0, stream>>>(ei, degree, E);
    scan_kernel<<<1, 1024, 0, stream>>>(degree, offsets, logsum, N);
    fill_kernel<<<(E + 255) / 256, 256, 0, stream>>>(ei, offsets, cursor, csr_src, E);
    agg_kernel<<<(Mpad * 64 + 255) / 256, 256, 0, stream>>>(x, csr_src, offsets, logsum,
                                                            Zhi, Zlo, ampv, attv, N, Mpad);
    wbuild_kernel<<<(NGEMM * KDIM + 255) / 256, 256, 0, stream>>>(Wmsg, Wroot, Whi, Wlo);
    gemm_kernel<<<nblk, 512, 0, stream>>>(Zhi, Zlo, Whi, Wlo, ampv, attv, bmsg, broot, out, N);
}

// Round 6
// 438.211 us; speedup vs baseline: 1.0152x; 1.0152x over previous
//
#include <hip/hip_runtime.h>
#include <cmath>

#define IN_CH 128
#define OUT_CH 128
#define KDIM 512           // Z row: x(128) | sum(128) | mean(128) | max(128)
#define NGEMM 384          // W^T rows: permuted (colgroup, wavehalf, section, ocol16)

typedef __attribute__((ext_vector_type(8))) short bfrag;   // 8 bf16 in 4 VGPRs
typedef __attribute__((ext_vector_type(4))) float f32x4;

// float -> bf16 round-to-nearest-even (bit pattern)
__device__ __forceinline__ unsigned short f2bf(float f) {
    unsigned int u = __float_as_uint(f);
    return (unsigned short)((u + 0x7FFFu + ((u >> 16) & 1u)) >> 16);
}
__device__ __forceinline__ float bf2f(unsigned short h) {
    return __uint_as_float(((unsigned int)h) << 16);
}

// async 16B global->LDS; HW uses first-lane LDS base + lane*16 (we pass the
// matching per-lane pointer so intent == behavior). Global side is a gather.
__device__ __forceinline__ void gl2lds16(const void* g, void* l) {
    __builtin_amdgcn_global_load_lds(
        (const __attribute__((address_space(1))) unsigned int*)g,
        (__attribute__((address_space(3))) unsigned int*)l, 16, 0, 0);
}

// ---------------- CSR build ----------------

__global__ void degree_kernel(const int* __restrict__ ei, int* __restrict__ degree, int E) {
    int e = blockIdx.x * blockDim.x + threadIdx.x;
    if (e < E) atomicAdd(&degree[ei[E + e]], 1);
}

__global__ __launch_bounds__(1024) void scan_kernel(const int* __restrict__ degree,
                                                    int* __restrict__ offsets,
                                                    float* __restrict__ logsum, int n) {
    const int T = 1024;
    int tid = threadIdx.x;
    int chunk = (n + T - 1) / T;
    int beg = min(tid * chunk, n);
    int end = min(beg + chunk, n);
    int s = 0;
    float ls = 0.f;
    for (int i = beg; i < end; ++i) {
        int d = degree[i];
        s += d;
        ls += logf((float)d + 2.0f);   // == log1p(d+1)
    }
    __shared__ int part[T];
    __shared__ float fl[T];
    part[tid] = s;
    fl[tid] = ls;
    __syncthreads();
    for (int off = 1; off < T; off <<= 1) {
        int v = (tid >= off) ? part[tid - off] : 0;
        __syncthreads();
        part[tid] += v;
        __syncthreads();
    }
    for (int off = T / 2; off > 0; off >>= 1) {
        if (tid < off) fl[tid] += fl[tid + off];
        __syncthreads();
    }
    if (tid == 0) logsum[0] = fl[0];
    int prefix = (tid == 0) ? 0 : part[tid - 1];
    for (int i = beg; i < end; ++i) {
        offsets[i] = prefix;
        prefix += degree[i];
    }
    if (tid == T - 1) offsets[n] = prefix;
}

__global__ void fill_kernel(const int* __restrict__ ei, const int* __restrict__ offsets,
                            int* __restrict__ cursor, int* __restrict__ csr_src, int E) {
    int e = blockIdx.x * blockDim.x + threadIdx.x;
    if (e < E) {
        int src = ei[e];
        int dst = ei[E + e];
        int pos = offsets[dst] + atomicAdd(&cursor[dst], 1);
        csr_src[pos] = src;
    }
}

// ---------------- Aggregation: one WAVE per node, lane = 2 channels ----------------

__global__ __launch_bounds__(256) void agg_kernel(const float* __restrict__ x,
                                                  const int* __restrict__ csr_src,
                                                  const int* __restrict__ offsets,
                                                  const float* __restrict__ logsum,
                                                  unsigned short* __restrict__ Zhi,
                                                  unsigned short* __restrict__ Zlo,
                                                  float* __restrict__ ampv,
                                                  float* __restrict__ attv,
                                                  int N, int Mpad) {
    int node = (blockIdx.x * 256 + threadIdx.x) >> 6;
    int lane = threadIdx.x & 63;
    if (node >= Mpad) return;
    long zoff = (long)node * KDIM + lane * 2;
    if (node >= N) {   // pad rows: zero so GEMM reads are harmless
        #pragma unroll
        for (int sec = 0; sec < 4; ++sec) {
            *(unsigned int*)&Zhi[zoff + sec * 128] = 0u;
            *(unsigned int*)&Zlo[zoff + sec * 128] = 0u;
        }
        return;
    }
    int beg = offsets[node], end = offsets[node + 1];
    const float NEG = -3.402823466e38f;
    float2 s[8], m[8];
    #pragma unroll
    for (int u = 0; u < 8; ++u) { s[u] = make_float2(0.f, 0.f); m[u] = make_float2(NEG, NEG); }
    int i = beg;
    for (; i + 8 <= end; i += 8) {
        int idx[8];
        #pragma unroll
        for (int u = 0; u < 8; ++u) idx[u] = csr_src[i + u];
        float2 v[8];
        #pragma unroll
        for (int u = 0; u < 8; ++u) v[u] = *(const float2*)&x[(long)idx[u] * IN_CH + lane * 2];
        #pragma unroll
        for (int u = 0; u < 8; ++u) {
            s[u].x += v[u].x; s[u].y += v[u].y;
            m[u].x = fmaxf(m[u].x, v[u].x); m[u].y = fmaxf(m[u].y, v[u].y);
        }
    }
    for (; i < end; ++i) {
        int n0 = csr_src[i];
        float2 v0 = *(const float2*)&x[(long)n0 * IN_CH + lane * 2];
        s[0].x += v0.x; s[0].y += v0.y;
        m[0].x = fmaxf(m[0].x, v0.x); m[0].y = fmaxf(m[0].y, v0.y);
    }
    #pragma unroll
    for (int u = 4; u < 8; ++u) {
        s[u - 4].x += s[u].x; s[u - 4].y += s[u].y;
        m[u - 4].x = fmaxf(m[u - 4].x, m[u].x); m[u - 4].y = fmaxf(m[u - 4].y, m[u].y);
    }
    float2 sum = make_float2((s[0].x + s[1].x) + (s[2].x + s[3].x),
                             (s[0].y + s[1].y) + (s[2].y + s[3].y));
    float2 mx = make_float2(fmaxf(fmaxf(m[0].x, m[1].x), fmaxf(m[2].x, m[3].x)),
                            fmaxf(fmaxf(m[0].y, m[1].y), fmaxf(m[2].y, m[3].y)));
    int deg = end - beg;
    float inv = 1.0f / fmaxf((float)deg, 1.0f);
    float2 mean = make_float2(sum.x * inv, sum.y * inv);
    if (deg == 0) { mx.x = 0.f; mx.y = 0.f; }
    float2 xv = *(const float2*)&x[(long)node * IN_CH + lane * 2];

    float2 secs[4] = { xv, sum, mean, mx };
    #pragma unroll
    for (int sec = 0; sec < 4; ++sec) {
        float a = secs[sec].x, b = secs[sec].y;
        unsigned short ha = f2bf(a), hb = f2bf(b);
        float la = a - bf2f(ha), lb = b - bf2f(hb);
        unsigned int hi = (unsigned int)ha | ((unsigned int)hb << 16);
        unsigned int lo = (unsigned int)f2bf(la) | ((unsigned int)f2bf(lb) << 16);
        *(unsigned int*)&Zhi[zoff + sec * 128] = hi;
        *(unsigned int*)&Zlo[zoff + sec * 128] = lo;
    }
    if (lane == 0) {
        float ref = fmaxf(logsum[0] / (float)N, 1.0f);
        float dt = log1pf((float)deg + 1.0f);
        ampv[node] = dt / ref;
        attv[node] = ref / fmaxf(dt, 1e-6f);
    }
}

// ---------------- Weight build: permuted row-major W^T, bf16 hi/lo -----------------
// W^T row jp = cg*96 + s16*16 + r16, s16 in [0,6): wn = s16/3, sec = s16%3,
// ocol = cg*32 + wn*16 + r16. Value = combined-W column (sec, ocol), row k.
// So GEMM block (cg) stages rows [96cg, 96cg+96); wave wn owns stripes
// {3wn, 3wn+1, 3wn+2} = sections 0,1,2 of the SAME 16 output cols -> wave-local
// amp/att epilogue.

__global__ void wbuild_kernel(const float* __restrict__ Wmsg, const float* __restrict__ Wroot,
                              unsigned short* __restrict__ Whi, unsigned short* __restrict__ Wlo) {
    int idx = blockIdx.x * 256 + threadIdx.x;
    if (idx >= NGEMM * KDIM) return;
    int jp = idx >> 9;       // 0..383
    int k = idx & 511;
    int cg = jp / 96;
    int rem = jp - cg * 96;
    int s16 = rem >> 4;
    int r16 = rem & 15;
    int wn = s16 / 3;
    int sec = s16 - wn * 3;
    int ocol = cg * 32 + wn * 16 + r16;
    float v;
    if (k < 128) {
        v = (sec == 0) ? Wroot[ocol * 128 + k] : 0.f;
    } else {
        int a = (k - 128) >> 7;
        int c = (k - 128) & 127;
        v = Wmsg[ocol * 1152 + (a * 3 + sec) * 128 + c];
    }
    unsigned short h = f2bf(v);
    Whi[idx] = h;
    Wlo[idx] = f2bf(v - bf2f(h));
}

// ---------------- MFMA GEMM, m97-style LDS staging --------------------------------
// out[M,128] = epilogue( Z[M,512] @ Wt^T ), BM=128, BN=96, BK=64,
// K interleaved: 3 phases (Zhi*Whi, Zhi*Wlo, Zlo*Whi) x 8 iters = 24 iters.
// 256 thr = 2x2 waves, wave tile 64x48 (4x3 MFMA tiles), acc = 48 AGPR.
// LDS frag-ordered: A chunk(mt,ks,lane) at (mt*128+ks*64+lane)*16B; B after 16KB.
// Staging: 4 A + 3 B global_load_lds (16B) per thread per iter; ds_read_b128 frags.

__global__ __launch_bounds__(256, 3) void gemm_kernel(const unsigned short* __restrict__ Zhi,
                                                      const unsigned short* __restrict__ Zlo,
                                                      const unsigned short* __restrict__ Whi,
                                                      const unsigned short* __restrict__ Wlo,
                                                      const float* __restrict__ ampv,
                                                      const float* __restrict__ attv,
                                                      const float* __restrict__ bmsg,
                                                      const float* __restrict__ broot,
                                                      float* __restrict__ out, int M) {
    __shared__ unsigned short lds[14336];   // 28 KB: A 16KB | B 12KB
    const int tid = threadIdx.x;
    const int w = tid >> 6;                 // wave 0..3
    const int lane = tid & 63;
    const int wm = w >> 1, wn = w & 1;
    const int row0 = blockIdx.x * 128;
    const int cg = blockIdx.y;              // 0..3 col-group (32 ocols)
    const int r16 = lane & 15, q = lane >> 4;

    // per-thread staging geometry (constant across iters)
    const int hb = tid >> 7;                // high bit of chunk row-group
    const int ks_s = (tid >> 6) & 1;        // staging k-half
    const int kst = ks_s * 32 + q * 8;      // k offset within BK for staged chunk
    long baseA[4];
    #pragma unroll
    for (int l = 0; l < 4; ++l)
        baseA[l] = (long)(row0 + (l * 2 + hb) * 16 + r16) * KDIM + kst;
    long baseB[3];
    #pragma unroll
    for (int l = 0; l < 3; ++l)
        baseB[l] = (long)(cg * 96 + (l * 2 + hb) * 16 + r16) * KDIM + kst;
    // LDS destinations (bytes): chunk c = l*256 + tid
    // frag-read chunk indices (ushort units = chunk*8)
    const int fragA0 = (wm * 4) * 128 + lane;          // + mt'*128 + ks*64
    const int fragB0 = 8192 / 8 * 8;                   // B region starts at ushort 8192

    const unsigned short* AS[3] = { Zhi, Zhi, Zlo };
    const unsigned short* BS[3] = { Whi, Wlo, Whi };

    f32x4 acc[4][3] = {};

    bool first = true;
    #pragma unroll 1
    for (int p = 0; p < 3; ++p) {
        const unsigned short* Asrc = AS[p];
        const unsigned short* Bsrc = BS[p];
        #pragma unroll 1
        for (int kk = 0; kk < 8; ++kk) {
            const int k0 = kk * 64;
            if (!first) __syncthreads();    // prior iter's ds_reads complete
            first = false;
            #pragma unroll
            for (int l = 0; l < 4; ++l)
                gl2lds16(Asrc + baseA[l] + k0, (char*)lds + (l * 256 + tid) * 16);
            #pragma unroll
            for (int l = 0; l < 3; ++l)
                gl2lds16(Bsrc + baseB[l] + k0, (char*)lds + 16384 + (l * 256 + tid) * 16);
            __syncthreads();                // staging visible (vmcnt drain)

            #pragma unroll
            for (int ks = 0; ks < 2; ++ks) {
                bfrag a[4], b[3];
                #pragma unroll
                for (int mt = 0; mt < 4; ++mt)
                    a[mt] = *(const bfrag*)&lds[((wm * 4 + mt) * 128 + ks * 64 + lane) * 8];
                #pragma unroll
                for (int t = 0; t < 3; ++t)
                    b[t] = *(const bfrag*)&lds[8192 + ((wn * 3 + t) * 128 + ks * 64 + lane) * 8];
                #pragma unroll
                for (int t = 0; t < 3; ++t)
                    #pragma unroll
                    for (int mt = 0; mt < 4; ++mt)
                        acc[mt][t] = __builtin_amdgcn_mfma_f32_16x16x32_bf16(a[mt], b[t], acc[mt][t], 0, 0, 0);
            }
        }
    }

    // fused epilogue: C/D layout col=lane&15, row=q*4+r (verified m89/m91)
    const int col = cg * 32 + wn * 16 + r16;
    const float bias = bmsg[col] + broot[col];
    #pragma unroll
    for (int mt = 0; mt < 4; ++mt) {
        #pragma unroll
        for (int r = 0; r < 4; ++r) {
            int row = row0 + wm * 64 + mt * 16 + q * 4 + r;
            if (row < M) {
                float v = acc[mt][0][r]
                        + ampv[row] * acc[mt][1][r]
                        + attv[row] * acc[mt][2][r] + bias;
                out[(long)row * OUT_CH + col] = v;
            }
        }
    }
}

// ---------------- Launch ----------------

extern "C" void kernel_launch(void* const* d_in, const int* in_sizes, int n_in,
                              void* d_out, int out_size, void* d_ws, size_t ws_size,
                              hipStream_t stream) {
    const float* x     = (const float*)d_in[0];
    const int*   ei    = (const int*)d_in[1];
    const float* Wmsg  = (const float*)d_in[2];
    const float* bmsg  = (const float*)d_in[3];
    const float* Wroot = (const float*)d_in[4];
    const float* broot = (const float*)d_in[5];
    float* out = (float*)d_out;

    int N = in_sizes[0] / IN_CH;           // 50000
    int E = in_sizes[1] / 2;               // 600000
    int Mb = (N + 127) / 128;              // 391
    int Mpad = Mb * 128;                   // 50048

    char* ws = (char*)d_ws;
    size_t off = 0;
    auto alloc = [&](size_t bytes) -> void* {
        void* p = ws + off;
        off = (off + bytes + 255) & ~(size_t)255;
        return p;
    };
    int* degree  = (int*)alloc((size_t)N * 4);
    int* offsets = (int*)alloc((size_t)(N + 1) * 4);
    int* cursor  = (int*)alloc((size_t)N * 4);
    float* logsum = (float*)alloc(4);
    int* csr_src = (int*)alloc((size_t)E * 4);
    unsigned short* Whi = (unsigned short*)alloc((size_t)NGEMM * KDIM * 2);
    unsigned short* Wlo = (unsigned short*)alloc((size_t)NGEMM * KDIM * 2);
    unsigned short* Zhi = (unsigned short*)alloc((size_t)Mpad * KDIM * 2);
    unsigned short* Zlo = (unsigned short*)alloc((size_t)Mpad * KDIM * 2);
    float* ampv = (float*)alloc((size_t)N * 4);
    float* attv = (float*)alloc((size_t)N * 4);

    hipMemsetAsync(degree, 0, (size_t)N * 4, stream);
    hipMemsetAsync(cursor, 0, (size_t)N * 4, stream);

    degree_kernel<<<(E + 255) / 256, 256, 0, stream>>>(ei, degree, E);
    scan_kernel<<<1, 1024, 0, stream>>>(degree, offsets, logsum, N);
    fill_kernel<<<(E + 255) / 256, 256, 0, stream>>>(ei, offsets, cursor, csr_src, E);
    agg_kernel<<<(Mpad * 64 + 255) / 256, 256, 0, stream>>>(x, csr_src, offsets, logsum,
                                                            Zhi, Zlo, ampv, attv, N, Mpad);
    wbuild_kernel<<<(NGEMM * KDIM + 255) / 256, 256, 0, stream>>>(Wmsg, Wroot, Whi, Wlo);
    dim3 ggrid(Mb, 4);
    gemm_kernel<<<ggrid, 256, 0, stream>>>(Zhi, Zlo, Whi, Wlo, ampv, attv, bmsg, broot, out, N);
}